// Round 5
// baseline (227.432 us; speedup 1.0000x reference)
//
#include <hip/hip_runtime.h>
#include <math.h>

#define NB 2048
typedef float f32x4 __attribute__((ext_vector_type(4)));
typedef float f32x2 __attribute__((ext_vector_type(2)));

// pre[] float offsets (folded weights)
#define P_WAL 0
#define P_WBL 1024
#define P_WLBL 2048
#define P_WNAL 3072
#define P_WEFF 4096
#define P_BWA 4160
#define P_BWB 4176
#define P_BWL 4192
#define P_BWN 4208
#define P_C0  4224

// ws float offsets
#define WS_BNPART 4352
#define WS_COEF   135424

// segmented butterfly: reduces a[HALF*2] over lanes, halving regs per stage
#define BSTAGE(MASK, HALF)                                        \
  { const bool hi_ = (lane & (MASK)) != 0;                        \
    _Pragma("unroll")                                             \
    for (int k_ = 0; k_ < (HALF); ++k_) {                         \
      float mine_ = hi_ ? a[k_ + (HALF)] : a[k_];                 \
      float oth_  = hi_ ? a[k_] : a[k_ + (HALF)];                 \
      a[k_] = mine_ + __shfl_xor(oth_, (MASK));                   \
    } }

// ---------------------------------------------------------------- k0: fold weights
__global__ __launch_bounds__(256) void k0_pre(const float* __restrict__ W_lin,
                                              const float* __restrict__ b_lin,
                                              const float* __restrict__ W_att,
                                              const float* __restrict__ Wa,
                                              const float* __restrict__ Wb,
                                              const float* __restrict__ Wn,
                                              const float* __restrict__ Wl,
                                              float* __restrict__ pre) {
  int t = threadIdx.x;
  for (int i = t; i < 1024; i += 256) {
    int o = i >> 6, d = i & 63;
    float sa = 0.f, sb = 0.f;
    for (int c = 0; c < 32; ++c) {
      float wl = W_lin[c * 64 + d];
      sa += Wa[o * 32 + c] * wl;
      sb += Wb[o * 32 + c] * wl;
    }
    pre[P_WAL + i] = sa;
    pre[P_WBL + i] = sb;
  }
  if (t < 64) {
    float s = 0.f;
    for (int c = 0; c < 32; ++c) s += W_att[c] * W_lin[c * 64 + t];
    pre[P_WEFF + t] = s;
  }
  if (t < 16) {
    float sa = 0.f, sb = 0.f;
    for (int c = 0; c < 32; ++c) {
      sa += Wa[t * 32 + c] * b_lin[c];
      sb += Wb[t * 32 + c] * b_lin[c];
    }
    pre[P_BWA + t] = sa;
    pre[P_BWB + t] = sb;
  }
  if (t == 0) {
    float s = 0.f;
    for (int c = 0; c < 32; ++c) s += W_att[c] * b_lin[c];
    pre[P_C0] = s;
  }
  __syncthreads();
  for (int i = t; i < 1024; i += 256) {
    int p_ = i >> 6, d = i & 63;
    float sl = 0.f, sn = 0.f;
    for (int o = 0; o < 16; ++o) {
      sl += Wl[p_ * 16 + o] * pre[P_WBL + o * 64 + d];
      sn += Wn[p_ * 16 + o] * pre[P_WAL + o * 64 + d];
    }
    pre[P_WLBL + i] = sl;
    pre[P_WNAL + i] = sn;
  }
  if (t < 16) {
    float sl = 0.f, sn = 0.f;
    for (int o = 0; o < 16; ++o) {
      sl += Wl[t * 16 + o] * pre[P_BWB + o];
      sn += Wn[t * 16 + o] * pre[P_BWA + o];
    }
    pre[P_BWL + t] = sl;
    pre[P_BWN + t] = sn;
  }
}

// ---------------------------------------------------------------- k1: fully fused per-batch module (feat -> out, BN partials)
__global__ __launch_bounds__(512, 2) void k1_fused(
    const float* __restrict__ xl_all, const float* __restrict__ xg_all,
    const float* __restrict__ pre, const float* __restrict__ Wc_g,
    const float* __restrict__ Wd_g, float* __restrict__ out,
    float* __restrict__ bn_part) {
  // region1: phase1/2 {xaggi | scratch5 | pe | xagg_inter} overlaid by attn {comb}
  __shared__ __align__(16) char R1[46592];
  float* xaggi = (float*)R1;                                   // 128*68 f -> 34816 B
  f32x4 (*scratch5)[8][16] = (f32x4(*)[8][16])(R1 + 34816);    // 10240 B
  float* pe = (float*)(R1 + 45056);                            // 5*8 f
  float* xagg_inter = (float*)(R1 + 45216);                    // 5*64 f
  float (*comb)[19] = (float(*)[19])R1;                        // 512*19*4 = 38912 B (overlay)
  __shared__ f32x4 slabI[128][4];
  __shared__ f32x4 slabV[128][4];
  __shared__ float s_small[160];
  __shared__ float part1[2][32];
  __shared__ float part2[2][32];

  const int t = threadIdx.x;
  const int b = blockIdx.x;
  const int lane = t & 63;
  const int w = t >> 6;                 // 8 waves
  const int q = lane >> 4;
  const int i16 = lane & 15;

  const float* xl = xl_all + (size_t)b * (5 * 128 * 64);
  const f32x4 weff4 = ((const f32x4*)(pre + P_WEFF))[i16];
  const float c0 = pre[P_C0];

  // ---------------- phase 1: streaming softmax aggregation over x_local
  const float* xb = xl + (size_t)(16 * w + q) * 64 + 4 * i16;
  f32x4 xA[4], xB[4], acc[4];
  float Zk[4];
  #pragma unroll
  for (int k = 0; k < 4; ++k) {
    acc[k] = (f32x4)0.f;
    Zk[k] = 0.f;
    xA[k] = *(const f32x4*)(xb + k * 256);
  }
  #pragma unroll
  for (int m = 0; m < 5; ++m) {
    f32x4* xc = (m & 1) ? xB : xA;
    f32x4* xn = (m & 1) ? xA : xB;
    if (m < 4) {
      const float* np = xb + (size_t)(m + 1) * 8192;
      #pragma unroll
      for (int k = 0; k < 4; ++k) xn[k] = *(const f32x4*)(np + k * 256);
    }
    float a0, a1, a2, a3;
    {
      f32x4 p0 = xc[0] * weff4, p1 = xc[1] * weff4, p2 = xc[2] * weff4, p3 = xc[3] * weff4;
      a0 = p0.x + p0.y + p0.z + p0.w;
      a1 = p1.x + p1.y + p1.z + p1.w;
      a2 = p2.x + p2.y + p2.z + p2.w;
      a3 = p3.x + p3.y + p3.z + p3.w;
    }
    #pragma unroll
    for (int mask = 1; mask <= 8; mask <<= 1) {
      a0 += __shfl_xor(a0, mask);
      a1 += __shfl_xor(a1, mask);
      a2 += __shfl_xor(a2, mask);
      a3 += __shfl_xor(a3, mask);
    }
    float e0 = __expf(a0 + c0), e1 = __expf(a1 + c0);
    float e2 = __expf(a2 + c0), e3 = __expf(a3 + c0);
    Zk[0] += e0; Zk[1] += e1; Zk[2] += e2; Zk[3] += e3;
    f32x4 pim;
    {
      f32x4 pr0 = e0 * xc[0];
      f32x4 pr1 = e1 * xc[1];
      f32x4 pr2 = e2 * xc[2];
      f32x4 pr3 = e3 * xc[3];
      acc[0] += pr0; acc[1] += pr1; acc[2] += pr2; acc[3] += pr3;
      pim = pr0 + pr1 + pr2 + pr3;
    }
    float se = e0 + e1 + e2 + e3;
    #pragma unroll
    for (int mask = 16; mask <= 32; mask <<= 1) {
      pim.x += __shfl_xor(pim.x, mask);
      pim.y += __shfl_xor(pim.y, mask);
      pim.z += __shfl_xor(pim.z, mask);
      pim.w += __shfl_xor(pim.w, mask);
      se += __shfl_xor(se, mask);
    }
    if (lane < 16) {
      scratch5[m][w][i16] = pim;
      if (i16 == 0) pe[m * 8 + w] = se;
    }
  }
  #pragma unroll
  for (int k = 0; k < 4; ++k) {
    float invz = 1.f / Zk[k];
    f32x4 v = acc[k] * invz;
    int r = 16 * w + 4 * k + q;
    *(f32x4*)&xaggi[r * 68 + 4 * i16] = v;
  }
  __syncthreads();

  // combine inter aggregates across waves, normalize
  if (t < 320) {
    int mm = t >> 6, d = t & 63;
    const float* sp = (const float*)&scratch5[mm][0][0];
    float s = 0.f;
    #pragma unroll
    for (int j = 0; j < 8; ++j) s += sp[j * 64 + d];
    float sume = pe[mm * 8 + 0] + pe[mm * 8 + 1] + pe[mm * 8 + 2] + pe[mm * 8 + 3] +
                 pe[mm * 8 + 4] + pe[mm * 8 + 5] + pe[mm * 8 + 6] + pe[mm * 8 + 7];
    xagg_inter[mm * 64 + d] = s / sume;
  }
  __syncthreads();

  // ---------------- phase 2: projections into LDS slabs (pk-f32 math)
  {
    const int q2 = __builtin_amdgcn_readfirstlane(t >> 7);   // 0..3 wave-uniform
    const int s2 = t & 127;
    const float* Wbase = pre + ((q2 < 2) ? P_WBL : P_WLBL) + (q2 & 1) * 512;
    const f32x2* xrow2 = (const f32x2*)&xaggi[s2 * 68];
    f32x2 a2[8];
    #pragma unroll
    for (int r = 0; r < 8; ++r) a2[r] = (f32x2)0.f;
    #pragma unroll
    for (int c2 = 0; c2 < 32; ++c2) {
      f32x2 xa = xrow2[c2];
      #pragma unroll
      for (int r = 0; r < 8; ++r)
        a2[r] += xa * *(const f32x2*)(Wbase + r * 64 + 2 * c2);
    }
    const int bb = ((q2 < 2) ? P_BWB : P_BWL) + (q2 & 1) * 8;
    f32x4* dst = ((q2 < 2) ? &slabI[s2][0] : &slabV[s2][0]) + (q2 & 1) * 2;
    f32x4 o0, o1;
    o0.x = a2[0].x + a2[0].y + pre[bb + 0];
    o0.y = a2[1].x + a2[1].y + pre[bb + 1];
    o0.z = a2[2].x + a2[2].y + pre[bb + 2];
    o0.w = a2[3].x + a2[3].y + pre[bb + 3];
    o1.x = a2[4].x + a2[4].y + pre[bb + 4];
    o1.y = a2[5].x + a2[5].y + pre[bb + 5];
    o1.z = a2[6].x + a2[6].y + pre[bb + 6];
    o1.w = a2[7].x + a2[7].y + pre[bb + 7];
    dst[0] = o0;
    dst[1] = o1;
  }
  // tiny inter projections -> s_small
  if (t < 160) {
    int o2 = t & 31, mm = t >> 5;
    const float* wr = pre + ((o2 < 16) ? (P_WAL + o2 * 64) : (P_WNAL + (o2 - 16) * 64));
    float p = 0.f;
    #pragma unroll
    for (int d = 0; d < 64; ++d) p += wr[d] * xagg_inter[mm * 64 + d];
    p += (o2 < 16) ? pre[P_BWA + o2] : pre[P_BWN + (o2 - 16)];
    if (o2 < 16) s_small[mm * 16 + o2] = p;
    else s_small[80 + mm * 16 + (o2 - 16)] = p;
  }

  // xlog for this thread's n (duplicated across j-groups; scalar Wc loads)
  const int n = t & 127;
  f32x2 xl2[8];
  {
    const f32x2* xgr = (const f32x2*)(xg_all + ((size_t)b * 128 + n) * 32);
    f32x2 xv[16];
    #pragma unroll
    for (int j = 0; j < 16; ++j) xv[j] = xgr[j];
    #pragma unroll
    for (int o2 = 0; o2 < 8; ++o2) {
      f32x2 r;
      #pragma unroll
      for (int jj = 0; jj < 2; ++jj) {
        const int o = o2 * 2 + jj;
        f32x2 s = (f32x2)0.f;
        #pragma unroll
        for (int j = 0; j < 16; ++j) s += xv[j] * *(const f32x2*)(Wc_g + o * 32 + 2 * j);
        r[jj] = s.x + s.y;
      }
      xl2[o2] = r;
    }
  }
  __syncthreads();

  // ---------------- phase 3: f_intra partial softmax-sum (4 threads per n)
  {
    const int j4 = t >> 7;               // 0..3: i-range [32*j4, 32*j4+32)
    float sum = 0.f;
    f32x2 fa2[8];
    #pragma unroll
    for (int j = 0; j < 8; ++j) fa2[j] = (f32x2)0.f;
    for (int i = 32 * j4; i < 32 * j4 + 32; ++i) {
      const f32x2* sI = (const f32x2*)&slabI[i][0];
      f32x2 d2 = xl2[0] * sI[0];
      #pragma unroll
      for (int j = 1; j < 8; ++j) d2 += xl2[j] * sI[j];
      float e = __expf(d2.x + d2.y);
      sum += e;
      f32x2 e2; e2.x = e; e2.y = e;
      const f32x2* sV = (const f32x2*)&slabV[i][0];
      #pragma unroll
      for (int j = 0; j < 8; ++j) fa2[j] += e2 * sV[j];
    }
    comb[t][0] = sum;
    #pragma unroll
    for (int j = 0; j < 8; ++j) { comb[t][1 + 2 * j] = fa2[j].x; comb[t][2 + 2 * j] = fa2[j].y; }
  }
  __syncthreads();

  // ---------------- phase 4: combine, f_inter, feat, BN partials (t<128)
  float fo[32];
  if (t < 128) {
    float tot = comb[n][0] + comb[n + 128][0] + comb[n + 256][0] + comb[n + 384][0];
    float inv = 1.f / tot;
    f32x2 fin2[8];
    #pragma unroll
    for (int j = 0; j < 8; ++j) {
      fin2[j].x = (comb[n][1 + 2 * j] + comb[n + 128][1 + 2 * j] +
                   comb[n + 256][1 + 2 * j] + comb[n + 384][1 + 2 * j]) * inv;
      fin2[j].y = (comb[n][2 + 2 * j] + comb[n + 128][2 + 2 * j] +
                   comb[n + 256][2 + 2 * j] + comb[n + 384][2 + 2 * j]) * inv;
    }
    // f_inter: 5-way softmax
    float L[5], mx3 = -1e30f;
    #pragma unroll
    for (int mm = 0; mm < 5; ++mm) {
      float p = 0.f;
      #pragma unroll
      for (int j = 0; j < 8; ++j) {
        p += xl2[j].x * s_small[mm * 16 + 2 * j];
        p += xl2[j].y * s_small[mm * 16 + 2 * j + 1];
      }
      L[mm] = p;
      mx3 = fmaxf(mx3, p);
    }
    float sum3 = 0.f;
    #pragma unroll
    for (int mm = 0; mm < 5; ++mm) { L[mm] = __expf(L[mm] - mx3); sum3 += L[mm]; }
    const float inv3 = 1.f / sum3;
    f32x2 fi2[8];
    #pragma unroll
    for (int j = 0; j < 8; ++j) {
      f32x2 r = (f32x2)0.f;
      #pragma unroll
      for (int mm = 0; mm < 5; ++mm) {
        r.x += L[mm] * s_small[80 + mm * 16 + 2 * j];
        r.y += L[mm] * s_small[80 + mm * 16 + 2 * j + 1];
      }
      fi2[j].x = r.x * inv3;
      fi2[j].y = r.y * inv3;
    }
    // feat[o] = Wd[o][0:16].fi + Wd[o][16:32].fin (pk math, scalar Wd loads)
    #pragma unroll
    for (int o = 0; o < 32; ++o) {
      const f32x2* wd = (const f32x2*)(Wd_g + o * 32);
      f32x2 s = fi2[0] * wd[0];
      #pragma unroll
      for (int j = 1; j < 8; ++j) s += fi2[j] * wd[j];
      #pragma unroll
      for (int j = 0; j < 8; ++j) s += fin2[j] * wd[8 + j];
      fo[o] = s.x + s.y;
    }
    float* op = out + ((size_t)b * 128 + n) * 32;
    #pragma unroll
    for (int o4 = 0; o4 < 8; ++o4)
      ((f32x4*)op)[o4] = *(f32x4*)&fo[4 * o4];
    // BN partials over the 2 active waves
    const int kmap = ((lane & 1) << 4) | ((lane & 2) << 2) | (lane & 4) |
                     ((lane >> 2) & 2) | ((lane >> 4) & 1);
    {
      float a[32];
      #pragma unroll
      for (int o = 0; o < 32; ++o) a[o] = fo[o];
      BSTAGE(1, 16) BSTAGE(2, 8) BSTAGE(4, 4) BSTAGE(8, 2) BSTAGE(16, 1)
      a[0] += __shfl_xor(a[0], 32);
      if (lane < 32) part1[w][kmap] = a[0];
    }
    {
      float a[32];
      #pragma unroll
      for (int o = 0; o < 32; ++o) a[o] = fo[o] * fo[o];
      BSTAGE(1, 16) BSTAGE(2, 8) BSTAGE(4, 4) BSTAGE(8, 2) BSTAGE(16, 1)
      a[0] += __shfl_xor(a[0], 32);
      if (lane < 32) part2[w][kmap] = a[0];
    }
  }
  __syncthreads();
  if (t < 64) {
    int c = t & 31, h = t >> 5;
    float v = h ? (part2[0][c] + part2[1][c]) : (part1[0][c] + part1[1][c]);
    bn_part[(size_t)b * 64 + h * 32 + c] = v;
  }
}

// ---------------------------------------------------------------- k2: BN coefficients (one block per channel)
__global__ __launch_bounds__(256, 1) void k2_stats(const float* __restrict__ bn_part,
                                                   const float* __restrict__ gamma,
                                                   const float* __restrict__ beta,
                                                   float* __restrict__ coef) {
  __shared__ float red[2][4];
  const int c = blockIdx.x;              // 0..31
  const int t = threadIdx.x;
  const int lane = t & 63, w = t >> 6;
  float s1 = 0.f, s2 = 0.f;
  for (int bb = t; bb < NB; bb += 256) {
    s1 += bn_part[(size_t)bb * 64 + c];
    s2 += bn_part[(size_t)bb * 64 + c + 32];
  }
  #pragma unroll
  for (int mask = 1; mask <= 32; mask <<= 1) {
    s1 += __shfl_xor(s1, mask);
    s2 += __shfl_xor(s2, mask);
  }
  if (lane == 0) { red[0][w] = s1; red[1][w] = s2; }
  __syncthreads();
  if (t == 0) {
    float S1 = red[0][0] + red[0][1] + red[0][2] + red[0][3];
    float S2 = red[1][0] + red[1][1] + red[1][2] + red[1][3];
    const float inv = 1.f / (float)(NB * 128);
    float mean = S1 * inv;
    float var = S2 * inv - mean * mean;
    float scl = gamma[c] * rsqrtf(var + 1e-5f);
    coef[c] = scl;
    coef[32 + c] = beta[c] - mean * scl;
  }
}

// ---------------------------------------------------------------- k3: BN apply + residual + leaky (in place)
__global__ __launch_bounds__(256) void k3_final(const float* __restrict__ xg,
                                                float* __restrict__ out,
                                                const float* __restrict__ coef) {
  __shared__ float s_c[64];
  if (threadIdx.x < 64) s_c[threadIdx.x] = coef[threadIdx.x];
  __syncthreads();
  size_t i4 = (size_t)blockIdx.x * 256 + threadIdx.x;
  float4 f = ((const float4*)out)[i4];
  float4 x = ((const float4*)xg)[i4];
  int c = (int)((i4 * 4) & 31);
  float4 r;
  r.x = x.x + f.x * s_c[c + 0] + s_c[32 + c + 0];
  r.y = x.y + f.y * s_c[c + 1] + s_c[32 + c + 1];
  r.z = x.z + f.z * s_c[c + 2] + s_c[32 + c + 2];
  r.w = x.w + f.w * s_c[c + 3] + s_c[32 + c + 3];
  r.x = r.x >= 0.f ? r.x : 0.2f * r.x;
  r.y = r.y >= 0.f ? r.y : 0.2f * r.y;
  r.z = r.z >= 0.f ? r.z : 0.2f * r.z;
  r.w = r.w >= 0.f ? r.w : 0.2f * r.w;
  ((float4*)out)[i4] = r;
}

// ----------------------------------------------------------------
extern "C" void kernel_launch(void* const* d_in, const int* in_sizes, int n_in,
                              void* d_out, int out_size, void* d_ws, size_t ws_size,
                              hipStream_t stream) {
  const float* xg    = (const float*)d_in[0];
  const float* xl    = (const float*)d_in[1];
  const float* W_lin = (const float*)d_in[2];
  const float* b_lin = (const float*)d_in[3];
  const float* W_att = (const float*)d_in[4];
  const float* Wa    = (const float*)d_in[5];
  const float* Wb    = (const float*)d_in[6];
  const float* Wc    = (const float*)d_in[7];
  const float* Wn    = (const float*)d_in[8];
  const float* Wl    = (const float*)d_in[9];
  const float* Wd    = (const float*)d_in[10];
  const float* gamma = (const float*)d_in[11];
  const float* beta  = (const float*)d_in[12];
  float* out = (float*)d_out;
  float* ws = (float*)d_ws;
  float* pre = ws;
  float* bn_part = ws + WS_BNPART;
  float* coef = ws + WS_COEF;

  hipLaunchKernelGGL(k0_pre, dim3(1), dim3(256), 0, stream,
                     W_lin, b_lin, W_att, Wa, Wb, Wn, Wl, pre);
  hipLaunchKernelGGL(k1_fused, dim3(NB), dim3(512), 0, stream,
                     xl, xg, pre, Wc, Wd, out, bn_part);
  hipLaunchKernelGGL(k2_stats, dim3(32), dim3(256), 0, stream, bn_part, gamma, beta, coef);
  hipLaunchKernelGGL(k3_final, dim3(8192), dim3(256), 0, stream, xg, out, coef);
}

// Round 6
// 220.308 us; speedup vs baseline: 1.0323x; 1.0323x over previous
//
#include <hip/hip_runtime.h>
#include <math.h>

#define NB 2048
typedef float f32x4 __attribute__((ext_vector_type(4)));
typedef float f32x2 __attribute__((ext_vector_type(2)));

// pre[] float offsets (folded weights)
#define P_WAL 0
#define P_WBL 1024
#define P_WLBL 2048
#define P_WNAL 3072
#define P_WEFF 4096
#define P_BWA 4160
#define P_BWB 4176
#define P_BWL 4192
#define P_BWN 4208
#define P_C0  4224

// ws float offsets
#define WS_BNPART 4352
#define WS_COEF   135424

__device__ __forceinline__ unsigned short f2bf(float f) {
  unsigned int u = __float_as_uint(f);
  u += 0x7fffu + ((u >> 16) & 1u);
  return (unsigned short)(u >> 16);
}
__device__ __forceinline__ unsigned int pack2bf(float lo, float hi) {
  return (unsigned int)f2bf(lo) | ((unsigned int)f2bf(hi) << 16);
}
__device__ __forceinline__ float bflo(unsigned int u) { return __uint_as_float(u << 16); }
__device__ __forceinline__ float bfhi(unsigned int u) { return __uint_as_float(u & 0xffff0000u); }

// segmented butterfly: reduces a[HALF*2] over lanes, halving regs per stage
#define BSTAGE(MASK, HALF)                                        \
  { const bool hi_ = (lane & (MASK)) != 0;                        \
    _Pragma("unroll")                                             \
    for (int k_ = 0; k_ < (HALF); ++k_) {                         \
      float mine_ = hi_ ? a[k_ + (HALF)] : a[k_];                 \
      float oth_  = hi_ ? a[k_] : a[k_ + (HALF)];                 \
      a[k_] = mine_ + __shfl_xor(oth_, (MASK));                   \
    } }

// ---------------------------------------------------------------- k0: fold weights
__global__ __launch_bounds__(256) void k0_pre(const float* __restrict__ W_lin,
                                              const float* __restrict__ b_lin,
                                              const float* __restrict__ W_att,
                                              const float* __restrict__ Wa,
                                              const float* __restrict__ Wb,
                                              const float* __restrict__ Wn,
                                              const float* __restrict__ Wl,
                                              float* __restrict__ pre) {
  int t = threadIdx.x;
  for (int i = t; i < 1024; i += 256) {
    int o = i >> 6, d = i & 63;
    float sa = 0.f, sb = 0.f;
    for (int c = 0; c < 32; ++c) {
      float wl = W_lin[c * 64 + d];
      sa += Wa[o * 32 + c] * wl;
      sb += Wb[o * 32 + c] * wl;
    }
    pre[P_WAL + i] = sa;
    pre[P_WBL + i] = sb;
  }
  if (t < 64) {
    float s = 0.f;
    for (int c = 0; c < 32; ++c) s += W_att[c] * W_lin[c * 64 + t];
    pre[P_WEFF + t] = s;
  }
  if (t < 16) {
    float sa = 0.f, sb = 0.f;
    for (int c = 0; c < 32; ++c) {
      sa += Wa[t * 32 + c] * b_lin[c];
      sb += Wb[t * 32 + c] * b_lin[c];
    }
    pre[P_BWA + t] = sa;
    pre[P_BWB + t] = sb;
  }
  if (t == 0) {
    float s = 0.f;
    for (int c = 0; c < 32; ++c) s += W_att[c] * b_lin[c];
    pre[P_C0] = s;
  }
  __syncthreads();
  for (int i = t; i < 1024; i += 256) {
    int p_ = i >> 6, d = i & 63;
    float sl = 0.f, sn = 0.f;
    for (int o = 0; o < 16; ++o) {
      sl += Wl[p_ * 16 + o] * pre[P_WBL + o * 64 + d];
      sn += Wn[p_ * 16 + o] * pre[P_WAL + o * 64 + d];
    }
    pre[P_WLBL + i] = sl;
    pre[P_WNAL + i] = sn;
  }
  if (t < 16) {
    float sl = 0.f, sn = 0.f;
    for (int o = 0; o < 16; ++o) {
      sl += Wl[t * 16 + o] * pre[P_BWB + o];
      sn += Wn[t * 16 + o] * pre[P_BWA + o];
    }
    pre[P_BWL + t] = sl;
    pre[P_BWN + t] = sn;
  }
}

// ---------------------------------------------------------------- k1: fused per-batch module
__global__ __launch_bounds__(512, 6) void k1_fused(
    const float* __restrict__ xl_all, const float* __restrict__ xg_all,
    const float* __restrict__ pre, const float* __restrict__ Wc_g,
    const float* __restrict__ Wd_g, float* __restrict__ out,
    float* __restrict__ bn_part) {
  __shared__ unsigned short xaggi[128 * 70];     // bf16, padded rows (17920 B)
  __shared__ float scratch5[5][8][64];           // per-m per-wave inter partials (10240 B)
  __shared__ float pe[5 * 8];
  __shared__ float xagg_inter[5 * 64];
  __shared__ f32x4 slabI[128][4];                // intra2T rows [s][16] (8192 B)
  __shared__ f32x4 slabV[128][4];                // v_intra rows [s][16] (8192 B)
  __shared__ float s_small[160];
  __shared__ float s_Wd[32][34];                 // padded (4352 B)
  __shared__ float part1[8][32];
  __shared__ float part2[8][32];

  const int t = threadIdx.x;
  const int b = blockIdx.x;
  const int lane = t & 63;
  const int w = t >> 6;                 // 8 waves
  const int q = lane >> 4;
  const int i16 = lane & 15;
  const int n2 = t >> 2;                // phase 3/4: n index
  const int q3 = t & 3;                 // phase 3/4: i-quarter / o-quarter

  const float* xl = xl_all + (size_t)b * (5 * 128 * 64);
  const f32x4 weff4 = ((const f32x4*)(pre + P_WEFF))[i16];
  const float c0 = pre[P_C0];

  // stage Wd into LDS
  for (int i = t; i < 1024; i += 512) s_Wd[i >> 5][i & 31] = Wd_g[i];

  // ---------------- phase 1: streaming softmax aggregation over x_local
  const float* xb = xl + (size_t)(16 * w + q) * 64 + 4 * i16;
  f32x4 xA[4], xB[4], acc[4];
  float Zk[4];
  #pragma unroll
  for (int k = 0; k < 4; ++k) {
    acc[k] = (f32x4)0.f;
    Zk[k] = 0.f;
    xA[k] = *(const f32x4*)(xb + k * 256);
  }
  #pragma unroll
  for (int m = 0; m < 5; ++m) {
    f32x4* xc = (m & 1) ? xB : xA;
    f32x4* xn = (m & 1) ? xA : xB;
    if (m < 4) {
      const float* np = xb + (size_t)(m + 1) * 8192;
      #pragma unroll
      for (int k = 0; k < 4; ++k) xn[k] = *(const f32x4*)(np + k * 256);
    }
    float a0, a1, a2, a3;
    {
      f32x4 p0 = xc[0] * weff4, p1 = xc[1] * weff4, p2 = xc[2] * weff4, p3 = xc[3] * weff4;
      a0 = p0.x + p0.y + p0.z + p0.w;
      a1 = p1.x + p1.y + p1.z + p1.w;
      a2 = p2.x + p2.y + p2.z + p2.w;
      a3 = p3.x + p3.y + p3.z + p3.w;
    }
    #pragma unroll
    for (int mask = 1; mask <= 8; mask <<= 1) {
      a0 += __shfl_xor(a0, mask);
      a1 += __shfl_xor(a1, mask);
      a2 += __shfl_xor(a2, mask);
      a3 += __shfl_xor(a3, mask);
    }
    float e0 = __expf(a0 + c0), e1 = __expf(a1 + c0);
    float e2 = __expf(a2 + c0), e3 = __expf(a3 + c0);
    Zk[0] += e0; Zk[1] += e1; Zk[2] += e2; Zk[3] += e3;
    f32x4 pim;
    {
      f32x4 pr0 = e0 * xc[0];
      f32x4 pr1 = e1 * xc[1];
      f32x4 pr2 = e2 * xc[2];
      f32x4 pr3 = e3 * xc[3];
      acc[0] += pr0; acc[1] += pr1; acc[2] += pr2; acc[3] += pr3;
      pim = pr0 + pr1 + pr2 + pr3;
    }
    float se = e0 + e1 + e2 + e3;
    #pragma unroll
    for (int mask = 16; mask <= 32; mask <<= 1) {
      pim.x += __shfl_xor(pim.x, mask);
      pim.y += __shfl_xor(pim.y, mask);
      pim.z += __shfl_xor(pim.z, mask);
      pim.w += __shfl_xor(pim.w, mask);
      se += __shfl_xor(se, mask);
    }
    if (lane < 16) {
      *(f32x4*)&scratch5[m][w][i16 * 4] = pim;
      if (i16 == 0) pe[m * 8 + w] = se;
    }
  }
  // normalize intra rows (thread-local) -> bf16 LDS
  #pragma unroll
  for (int k = 0; k < 4; ++k) {
    float invz = 1.f / Zk[k];
    f32x4 v = acc[k] * invz;
    int r = 16 * w + 4 * k + q;
    *(unsigned int*)&xaggi[r * 70 + 4 * i16]     = pack2bf(v.x, v.y);
    *(unsigned int*)&xaggi[r * 70 + 4 * i16 + 2] = pack2bf(v.z, v.w);
  }
  __syncthreads();  // bar1

  // ---------------- phase 2a: per-s projections into LDS slabs
  {
    const int q2 = __builtin_amdgcn_readfirstlane(t >> 7);   // 0..3 wave-uniform
    const int s2 = t & 127;
    const float* Wbase = pre + ((q2 < 2) ? P_WBL : P_WLBL) + (q2 & 1) * 512;
    const unsigned short* xrow = &xaggi[s2 * 70];
    f32x2 a2[8];
    #pragma unroll
    for (int r = 0; r < 8; ++r) a2[r] = (f32x2)0.f;
    #pragma unroll
    for (int c2 = 0; c2 < 32; ++c2) {
      unsigned int u = *(const unsigned int*)(xrow + 2 * c2);
      f32x2 xa;
      xa.x = bflo(u);
      xa.y = bfhi(u);
      #pragma unroll
      for (int r = 0; r < 8; ++r)
        a2[r] += xa * *(const f32x2*)(Wbase + r * 64 + 2 * c2);
    }
    const int bb = ((q2 < 2) ? P_BWB : P_BWL) + (q2 & 1) * 8;
    f32x4* dst = ((q2 < 2) ? &slabI[s2][0] : &slabV[s2][0]) + (q2 & 1) * 2;
    f32x4 o0, o1;
    o0.x = a2[0].x + a2[0].y + pre[bb + 0];
    o0.y = a2[1].x + a2[1].y + pre[bb + 1];
    o0.z = a2[2].x + a2[2].y + pre[bb + 2];
    o0.w = a2[3].x + a2[3].y + pre[bb + 3];
    o1.x = a2[4].x + a2[4].y + pre[bb + 4];
    o1.y = a2[5].x + a2[5].y + pre[bb + 5];
    o1.z = a2[6].x + a2[6].y + pre[bb + 6];
    o1.w = a2[7].x + a2[7].y + pre[bb + 7];
    dst[0] = o0;
    dst[1] = o1;
  }
  // combine inter aggregates across waves, normalize
  if (t < 320) {
    int mm = t >> 6, d = t & 63;
    float s = 0.f;
    #pragma unroll
    for (int j = 0; j < 8; ++j) s += scratch5[mm][j][d];
    float sume = pe[mm * 8 + 0] + pe[mm * 8 + 1] + pe[mm * 8 + 2] + pe[mm * 8 + 3] +
                 pe[mm * 8 + 4] + pe[mm * 8 + 5] + pe[mm * 8 + 6] + pe[mm * 8 + 7];
    xagg_inter[mm * 64 + d] = s / sume;
  }
  // issue xg loads early (latency hides under bar2)
  f32x2 xv[16];
  {
    const f32x2* xgr = (const f32x2*)(xg_all + ((size_t)b * 128 + n2) * 32);
    #pragma unroll
    for (int j = 0; j < 16; ++j) xv[j] = xgr[j];
  }
  __syncthreads();  // bar2

  // ---------------- phase 2b: tiny inter projections -> s_small
  if (t < 160) {
    int o2 = t & 31, mm = t >> 5;
    const float* wr = pre + ((o2 < 16) ? (P_WAL + o2 * 64) : (P_WNAL + (o2 - 16) * 64));
    float p = 0.f;
    #pragma unroll
    for (int d = 0; d < 64; ++d) p += wr[d] * xagg_inter[mm * 64 + d];
    p += (o2 < 16) ? pre[P_BWA + o2] : pre[P_BWN + (o2 - 16)];
    if (o2 < 16) s_small[mm * 16 + o2] = p;
    else s_small[80 + mm * 16 + (o2 - 16)] = p;
  }
  // xlog for n2 (4 q-partner threads compute identical copies)
  f32x2 xl2[8];
  #pragma unroll
  for (int o2 = 0; o2 < 8; ++o2) {
    f32x2 r;
    #pragma unroll
    for (int jj = 0; jj < 2; ++jj) {
      const int o = o2 * 2 + jj;
      f32x2 s = (f32x2)0.f;
      #pragma unroll
      for (int j = 0; j < 16; ++j) s += xv[j] * *(const f32x2*)(Wc_g + o * 32 + 2 * j);
      r[jj] = s.x + s.y;
    }
    xl2[o2] = r;
  }
  __syncthreads();  // bar3

  // ---------------- phase 3: f_intra partial sums, i = q3 + 4k (2-way-free banks)
  float sum = 0.f;
  f32x4 fav[4];
  #pragma unroll
  for (int c = 0; c < 4; ++c) fav[c] = (f32x4)0.f;
  for (int k = 0; k < 32; ++k) {
    const int i = q3 + 4 * k;
    f32x2 d2 = (f32x2)0.f;
    #pragma unroll
    for (int c = 0; c < 4; ++c) {
      f32x4 ch = slabI[i][c];
      f32x2 lo; lo.x = ch.x; lo.y = ch.y;
      f32x2 hi; hi.x = ch.z; hi.y = ch.w;
      d2 += xl2[2 * c] * lo;
      d2 += xl2[2 * c + 1] * hi;
    }
    float e = __expf(d2.x + d2.y);
    sum += e;
    #pragma unroll
    for (int c = 0; c < 4; ++c) fav[c] += e * slabV[i][c];
  }
  // combine the 4 q-partners (adjacent lanes) via shuffles
  sum += __shfl_xor(sum, 1);
  sum += __shfl_xor(sum, 2);
  #pragma unroll
  for (int c = 0; c < 4; ++c) {
    fav[c].x += __shfl_xor(fav[c].x, 1);
    fav[c].y += __shfl_xor(fav[c].y, 1);
    fav[c].z += __shfl_xor(fav[c].z, 1);
    fav[c].w += __shfl_xor(fav[c].w, 1);
    fav[c].x += __shfl_xor(fav[c].x, 2);
    fav[c].y += __shfl_xor(fav[c].y, 2);
    fav[c].z += __shfl_xor(fav[c].z, 2);
    fav[c].w += __shfl_xor(fav[c].w, 2);
  }
  const float inv = 1.f / sum;
  f32x2 fin2[8];
  #pragma unroll
  for (int j = 0; j < 8; ++j) {
    fin2[j].x = fav[j >> 1][2 * (j & 1)] * inv;
    fin2[j].y = fav[j >> 1][2 * (j & 1) + 1] * inv;
  }

  // ---------------- phase 4: f_inter, feat (o-quarter per lane), BN partials
  float L[5], mx3 = -1e30f;
  #pragma unroll
  for (int mm = 0; mm < 5; ++mm) {
    float p = 0.f;
    #pragma unroll
    for (int j = 0; j < 8; ++j) {
      p += xl2[j].x * s_small[mm * 16 + 2 * j];
      p += xl2[j].y * s_small[mm * 16 + 2 * j + 1];
    }
    L[mm] = p;
    mx3 = fmaxf(mx3, p);
  }
  float sum3 = 0.f;
  #pragma unroll
  for (int mm = 0; mm < 5; ++mm) { L[mm] = __expf(L[mm] - mx3); sum3 += L[mm]; }
  const float inv3 = 1.f / sum3;
  f32x2 fi2[8];
  #pragma unroll
  for (int j = 0; j < 8; ++j) {
    f32x2 r = (f32x2)0.f;
    #pragma unroll
    for (int mm = 0; mm < 5; ++mm) {
      r.x += L[mm] * s_small[80 + mm * 16 + 2 * j];
      r.y += L[mm] * s_small[80 + mm * 16 + 2 * j + 1];
    }
    fi2[j].x = r.x * inv3;
    fi2[j].y = r.y * inv3;
  }
  float fo[8];
  #pragma unroll
  for (int j = 0; j < 8; ++j) {
    const int o = 8 * q3 + j;
    const f32x2* wd = (const f32x2*)&s_Wd[o][0];
    f32x2 s = fi2[0] * wd[0];
    #pragma unroll
    for (int jj = 1; jj < 8; ++jj) s += fi2[jj] * wd[jj];
    #pragma unroll
    for (int jj = 0; jj < 8; ++jj) s += fin2[jj] * wd[8 + jj];
    fo[j] = s.x + s.y;
  }
  {
    float* op = out + ((size_t)b * 128 + n2) * 32 + 8 * q3;
    ((f32x4*)op)[0] = *(f32x4*)&fo[0];
    ((f32x4*)op)[1] = *(f32x4*)&fo[4];
  }
  // BN partials: reduce over the 16 same-q lanes (masks 4,8,16,32)
  const int omap = 8 * q3 + 4 * ((lane >> 2) & 1) + 2 * ((lane >> 3) & 1) + ((lane >> 4) & 1);
  {
    float a[8];
    #pragma unroll
    for (int j = 0; j < 8; ++j) a[j] = fo[j];
    BSTAGE(4, 4) BSTAGE(8, 2) BSTAGE(16, 1)
    a[0] += __shfl_xor(a[0], 32);
    if (lane < 32) part1[w][omap] = a[0];
  }
  {
    float a[8];
    #pragma unroll
    for (int j = 0; j < 8; ++j) a[j] = fo[j] * fo[j];
    BSTAGE(4, 4) BSTAGE(8, 2) BSTAGE(16, 1)
    a[0] += __shfl_xor(a[0], 32);
    if (lane < 32) part2[w][omap] = a[0];
  }
  __syncthreads();  // bar4
  if (t < 64) {
    int c = t & 31, h = t >> 5;
    float v = 0.f;
    #pragma unroll
    for (int j = 0; j < 8; ++j) v += h ? part2[j][c] : part1[j][c];
    bn_part[(size_t)b * 64 + h * 32 + c] = v;
  }
}

// ---------------------------------------------------------------- k2: BN coefficients (one block per channel)
__global__ __launch_bounds__(256, 1) void k2_stats(const float* __restrict__ bn_part,
                                                   const float* __restrict__ gamma,
                                                   const float* __restrict__ beta,
                                                   float* __restrict__ coef) {
  __shared__ float red[2][4];
  const int c = blockIdx.x;              // 0..31
  const int t = threadIdx.x;
  const int lane = t & 63, w = t >> 6;
  float s1 = 0.f, s2 = 0.f;
  for (int bb = t; bb < NB; bb += 256) {
    s1 += bn_part[(size_t)bb * 64 + c];
    s2 += bn_part[(size_t)bb * 64 + c + 32];
  }
  #pragma unroll
  for (int mask = 1; mask <= 32; mask <<= 1) {
    s1 += __shfl_xor(s1, mask);
    s2 += __shfl_xor(s2, mask);
  }
  if (lane == 0) { red[0][w] = s1; red[1][w] = s2; }
  __syncthreads();
  if (t == 0) {
    float S1 = red[0][0] + red[0][1] + red[0][2] + red[0][3];
    float S2 = red[1][0] + red[1][1] + red[1][2] + red[1][3];
    const float inv = 1.f / (float)(NB * 128);
    float mean = S1 * inv;
    float var = S2 * inv - mean * mean;
    float scl = gamma[c] * rsqrtf(var + 1e-5f);
    coef[c] = scl;
    coef[32 + c] = beta[c] - mean * scl;
  }
}

// ---------------------------------------------------------------- k3: BN apply + residual + leaky (in place)
__global__ __launch_bounds__(256) void k3_final(const float* __restrict__ xg,
                                                float* __restrict__ out,
                                                const float* __restrict__ coef) {
  __shared__ float s_c[64];
  if (threadIdx.x < 64) s_c[threadIdx.x] = coef[threadIdx.x];
  __syncthreads();
  size_t i4 = (size_t)blockIdx.x * 256 + threadIdx.x;
  float4 f = ((const float4*)out)[i4];
  float4 x = ((const float4*)xg)[i4];
  int c = (int)((i4 * 4) & 31);
  float4 r;
  r.x = x.x + f.x * s_c[c + 0] + s_c[32 + c + 0];
  r.y = x.y + f.y * s_c[c + 1] + s_c[32 + c + 1];
  r.z = x.z + f.z * s_c[c + 2] + s_c[32 + c + 2];
  r.w = x.w + f.w * s_c[c + 3] + s_c[32 + c + 3];
  r.x = r.x >= 0.f ? r.x : 0.2f * r.x;
  r.y = r.y >= 0.f ? r.y : 0.2f * r.y;
  r.z = r.z >= 0.f ? r.z : 0.2f * r.z;
  r.w = r.w >= 0.f ? r.w : 0.2f * r.w;
  ((float4*)out)[i4] = r;
}

// ----------------------------------------------------------------
extern "C" void kernel_launch(void* const* d_in, const int* in_sizes, int n_in,
                              void* d_out, int out_size, void* d_ws, size_t ws_size,
                              hipStream_t stream) {
  const float* xg    = (const float*)d_in[0];
  const float* xl    = (const float*)d_in[1];
  const float* W_lin = (const float*)d_in[2];
  const float* b_lin = (const float*)d_in[3];
  const float* W_att = (const float*)d_in[4];
  const float* Wa    = (const float*)d_in[5];
  const float* Wb    = (const float*)d_in[6];
  const float* Wc    = (const float*)d_in[7];
  const float* Wn    = (const float*)d_in[8];
  const float* Wl    = (const float*)d_in[9];
  const float* Wd    = (const float*)d_in[10];
  const float* gamma = (const float*)d_in[11];
  const float* beta  = (const float*)d_in[12];
  float* out = (float*)d_out;
  float* ws = (float*)d_ws;
  float* pre = ws;
  float* bn_part = ws + WS_BNPART;
  float* coef = ws + WS_COEF;

  hipLaunchKernelGGL(k0_pre, dim3(1), dim3(256), 0, stream,
                     W_lin, b_lin, W_att, Wa, Wb, Wn, Wl, pre);
  hipLaunchKernelGGL(k1_fused, dim3(NB), dim3(512), 0, stream,
                     xl, xg, pre, Wc, Wd, out, bn_part);
  hipLaunchKernelGGL(k2_stats, dim3(32), dim3(256), 0, stream, bn_part, gamma, beta, coef);
  hipLaunchKernelGGL(k3_final, dim3(8192), dim3(256), 0, stream, xg, out, coef);
}